// Round 6
// baseline (325.963 us; speedup 1.0000x reference)
//
#include <hip/hip_runtime.h>
#include <math.h>

#define L_MAX 2048
#define BATCH 64
#define DIM   256
#define CCH   512
#define ROWSTRIDE (BATCH * DIM)   // floats between consecutive l at fixed b
#define NCHUNK 128                // l-chunks of 16

// ws layout (floats):
#define HQ_OFF   0                // 64*256   = 16384
#define WF_OFF   16384            // 3*256    = 768
#define HARD_OFF 17152            // 2048*64  = 131072
#define PART_OFF 148224           // 128*64*256 = 2097152
#define CNTS_OFF 2245376          // 128*64   = 8192

__device__ __forceinline__ float fast_tanh(float x) {
    float ax = fabsf(x);
    float e  = __expf(2.0f * ax);                       // inf for big ax -> r=1
    float r  = 1.0f - 2.0f * __builtin_amdgcn_rcpf(e + 1.0f);
    return copysignf(r, x);
}

// Kernel A: hq[b][d] = sum_k ht_query[b][k]*W_query[d][k]
//           wf[j][d] = sum_c W_conv[c][0][j]*W_att_past[d][c]
__global__ __launch_bounds__(256) void prep_kernel(
    const float* __restrict__ ht_query, const float* __restrict__ W_query,
    const float* __restrict__ W_conv,   const float* __restrict__ W_att_past,
    float* __restrict__ hq, float* __restrict__ wf) {
    int t   = threadIdx.x;
    int blk = blockIdx.x;
    __shared__ float q[DIM];
    if (blk < BATCH) {
        q[t] = ht_query[blk * DIM + t];
        __syncthreads();
        const float4* wrow = (const float4*)(W_query + t * DIM);
        float acc = 0.f;
        #pragma unroll 8
        for (int k = 0; k < DIM / 4; k++) {
            float4 wv = wrow[k];
            acc += q[4*k] * wv.x + q[4*k+1] * wv.y + q[4*k+2] * wv.z + q[4*k+3] * wv.w;
        }
        hq[blk * DIM + t] = acc;
    } else {
        int j = blk - BATCH;
        const float4* wrow = (const float4*)(W_att_past + t * CCH);
        float acc = 0.f;
        #pragma unroll 8
        for (int c = 0; c < CCH / 4; c++) {
            float4 wv = wrow[c];
            acc += W_conv[(4*c  ) * 3 + j] * wv.x + W_conv[(4*c+1) * 3 + j] * wv.y
                 + W_conv[(4*c+2) * 3 + j] * wv.z + W_conv[(4*c+3) * 3 + j] * wv.w;
        }
        wf[j * DIM + t] = acc;
    }
}

// Fused: score + hard + partial ct. SMALL per-wave work, MANY waves:
// block = (b, chunk of 16 l's); 4 waves x 4 rows each. 8192 blocks = 32/CU.
// Per wave: 4-row key burst (16 VGPRs), scores+butterfly, 4 conditional val
// loads (h==0 rows aliased to tile row 0, L2-hot), LDS cross-wave reduce.
// No atomics: per-block cnt -> cnts[chunk*64+b].
__global__ __launch_bounds__(256) void fused_kernel(
    const float* __restrict__ ctx_key, const float* __restrict__ ctx_val,
    const float* __restrict__ ctx_mask, const float* __restrict__ att_past,
    const float* __restrict__ hq, const float* __restrict__ wf,
    const float* __restrict__ b_att_past, const float* __restrict__ W_attn,
    const float* __restrict__ b_attn,
    float* __restrict__ hard_raw, float* __restrict__ cnts,
    float* __restrict__ part) {
    int b     = blockIdx.x & 63;
    int chunk = blockIdx.x >> 6;
    int w     = threadIdx.x >> 6;
    int lane  = threadIdx.x & 63;
    int d0    = lane << 2;
    int l0    = chunk * 16 + w * 4;

    float4 hq4 = *(const float4*)(hq + b * DIM + d0);
    float4 bp  = *(const float4*)(b_att_past + d0);
    hq4.x += bp.x; hq4.y += bp.y; hq4.z += bp.z; hq4.w += bp.w;
    float4 w0  = *(const float4*)(wf + d0);
    float4 w1  = *(const float4*)(wf + DIM + d0);
    float4 w2  = *(const float4*)(wf + 2 * DIM + d0);
    float4 wa  = *(const float4*)(W_attn + d0);
    float battn = b_attn[0];
    const float* apb = att_past + b * L_MAX;

    // att_past window [l0-1, l0+4]: ap[i] = apb[l0-1+i]
    float ap[6];
    {
        float4 t0 = *(const float4*)(apb + l0);
        ap[1] = t0.x; ap[2] = t0.y; ap[3] = t0.z; ap[4] = t0.w;
        ap[0] = (l0 > 0)         ? apb[l0 - 1] : 0.f;
        ap[5] = (l0 + 4 < L_MAX) ? apb[l0 + 4] : 0.f;
    }

    const float* key_base = ctx_key + (size_t)(l0 * BATCH + b) * DIM + d0;
    const float* val_base = ctx_val + (size_t)(l0 * BATCH + b) * DIM + d0;

    // ---- key burst + masks ----
    float4 k4[4];
    float m4[4];
    #pragma unroll
    for (int j = 0; j < 4; j++)
        k4[j] = *(const float4*)(key_base + (size_t)j * ROWSTRIDE);
    #pragma unroll
    for (int j = 0; j < 4; j++)
        m4[j] = ctx_mask[(l0 + j) * BATCH + b];

    // ---- scores + butterfly (result identical in all lanes) ----
    float p[4];
    #pragma unroll
    for (int j = 0; j < 4; j++) {
        float am = ap[j], a0 = ap[j + 1], a1 = ap[j + 2];
        float x0 = k4[j].x + hq4.x + am * w0.x + a0 * w1.x + a1 * w2.x;
        float x1 = k4[j].y + hq4.y + am * w0.y + a0 * w1.y + a1 * w2.y;
        float x2 = k4[j].z + hq4.z + am * w0.z + a0 * w1.z + a1 * w2.z;
        float x3 = k4[j].w + hq4.w + am * w0.w + a0 * w1.w + a1 * w2.w;
        p[j] = fast_tanh(x0) * wa.x + fast_tanh(x1) * wa.y +
               fast_tanh(x2) * wa.z + fast_tanh(x3) * wa.w;
    }
    #pragma unroll
    for (int off = 32; off > 0; off >>= 1) {
        #pragma unroll
        for (int j = 0; j < 4; j++)
            p[j] += __shfl_xor(p[j], off, 64);
    }

    float h[4];
    float cnt = 0.f;
    #pragma unroll
    for (int j = 0; j < 4; j++) {
        h[j] = (p[j] + battn >= 0.f) ? m4[j] : 0.f;
        cnt += h[j];
    }
    if (lane == 0) {
        #pragma unroll
        for (int j = 0; j < 4; j++)
            hard_raw[(l0 + j) * BATCH + b] = h[j];
    }

    // ---- branchless val burst; h==0 rows alias tile row 0 ----
    float4 v4[4];
    #pragma unroll
    for (int j = 0; j < 4; j++) {
        size_t off = (h[j] != 0.f) ? (size_t)j * ROWSTRIDE : 0;
        v4[j] = *(const float4*)(val_base + off);
    }
    float4 acc = make_float4(0.f, 0.f, 0.f, 0.f);
    #pragma unroll
    for (int j = 0; j < 4; j++) {
        acc.x += v4[j].x * h[j]; acc.y += v4[j].y * h[j];
        acc.z += v4[j].z * h[j]; acc.w += v4[j].w * h[j];
    }

    __shared__ float red[4 * DIM];
    __shared__ float c4[4];
    *(float4*)(red + w * DIM + d0) = acc;
    if (lane == 0) c4[w] = cnt;
    __syncthreads();
    int d = threadIdx.x;
    float s = red[d] + red[DIM + d] + red[2 * DIM + d] + red[3 * DIM + d];
    part[(size_t)(chunk * BATCH + b) * DIM + d] = s;
    if (threadIdx.x == 0)
        cnts[chunk * BATCH + b] = c4[0] + c4[1] + c4[2] + c4[3];
}

// Tail: blocks 0..63   -> ct[b][d] = (sum_chunk part) / (Z_b+1e-10)
//       blocks 64..191 -> out_hard[l][b] = hard_raw[l][b] / (Z_b+1e-10)
// Z_b recomputed from cnts[] in each half (8 KB, L2-hot) -- no ordering dep.
__global__ __launch_bounds__(256) void tail_kernel(
    const float* __restrict__ part, const float* __restrict__ hard_raw,
    const float* __restrict__ cnts,
    float* __restrict__ ct, float* __restrict__ out_hard) {
    if (blockIdx.x < BATCH) {
        int b = blockIdx.x;
        int d = threadIdx.x;
        float z = 0.f;
        #pragma unroll 8
        for (int c = 0; c < NCHUNK; c++) z += cnts[c * BATCH + b];
        float s = 0.f;
        #pragma unroll 8
        for (int c = 0; c < NCHUNK; c++)
            s += part[(size_t)(c * BATCH + b) * DIM + d];
        ct[b * DIM + d] = s / (z + 1e-10f);
    } else {
        __shared__ float zs[BATCH];
        int t = threadIdx.x;
        if (t < BATCH) {
            float z = 0.f;
            #pragma unroll 8
            for (int c = 0; c < NCHUNK; c++) z += cnts[c * BATCH + t];
            zs[t] = z;
        }
        __syncthreads();
        int i = (blockIdx.x - BATCH) * 256 + t;          // 4 elems each
        float4 h = *(const float4*)(hard_raw + (size_t)i * 4);
        int b0 = (i * 4) & 63;
        float4 o;
        o.x = h.x / (zs[b0 + 0] + 1e-10f);
        o.y = h.y / (zs[b0 + 1] + 1e-10f);
        o.z = h.z / (zs[b0 + 2] + 1e-10f);
        o.w = h.w / (zs[b0 + 3] + 1e-10f);
        *(float4*)(out_hard + (size_t)i * 4) = o;
    }
}

extern "C" void kernel_launch(void* const* d_in, const int* in_sizes, int n_in,
                              void* d_out, int out_size, void* d_ws, size_t ws_size,
                              hipStream_t stream) {
    const float* ctx_val    = (const float*)d_in[0];
    const float* ctx_key    = (const float*)d_in[1];
    const float* ctx_mask   = (const float*)d_in[2];
    const float* att_past   = (const float*)d_in[3];
    const float* ht_query   = (const float*)d_in[4];
    const float* W_conv     = (const float*)d_in[5];
    const float* W_query    = (const float*)d_in[6];
    const float* W_att_past = (const float*)d_in[7];
    const float* b_att_past = (const float*)d_in[8];
    const float* W_attn     = (const float*)d_in[9];
    const float* b_attn     = (const float*)d_in[10];

    float* ws   = (float*)d_ws;
    float* hq   = ws + HQ_OFF;
    float* wf   = ws + WF_OFF;
    float* hard = ws + HARD_OFF;
    float* part = ws + PART_OFF;
    float* cnts = ws + CNTS_OFF;

    float* out_ct   = (float*)d_out;                 // (64,256)
    float* out_hard = (float*)d_out + BATCH * DIM;   // (2048,64)

    prep_kernel<<<BATCH + 3, 256, 0, stream>>>(
        ht_query, W_query, W_conv, W_att_past, hq, wf);

    fused_kernel<<<BATCH * NCHUNK, 256, 0, stream>>>(
        ctx_key, ctx_val, ctx_mask, att_past, hq, wf, b_att_past, W_attn, b_attn,
        hard, cnts, part);

    tail_kernel<<<BATCH + 128, 256, 0, stream>>>(part, hard, cnts, out_ct, out_hard);
}